// Round 1
// baseline (1968.081 us; speedup 1.0000x reference)
//
#include <hip/hip_runtime.h>

#define D_FEAT 32

// One thread per (edge, float4-group): gathers 16B of h[src], scales by w,
// scatter-adds into hn[dst] with 4 global f32 atomics.
__global__ void spmm_scatter(const int* __restrict__ src, const int* __restrict__ dst,
                             const float* __restrict__ w, const float* __restrict__ h,
                             float* __restrict__ hn, int nE) {
    int i = blockIdx.x * blockDim.x + threadIdx.x;
    int total = nE * 8;           // 8 float4 groups per edge (D=32)
    if (i >= total) return;
    int e = i >> 3;
    int g = i & 7;
    int s = src[e];
    int t = dst[e];
    float wt = w[e];
    float4 v = reinterpret_cast<const float4*>(h)[(size_t)s * 8 + g];
    float* p = hn + (size_t)t * D_FEAT + g * 4;
    atomicAdd(p + 0, v.x * wt);
    atomicAdd(p + 1, v.y * wt);
    atomicAdd(p + 2, v.z * wt);
    atomicAdd(p + 3, v.w * wt);
}

// out = emb + hn   (layer 0 accumulate; also initializes out, overwriting poison)
__global__ void accum_first(const float* __restrict__ emb, const float* __restrict__ hn,
                            float* __restrict__ out, int n4) {
    int i = blockIdx.x * blockDim.x + threadIdx.x;
    if (i >= n4) return;
    float4 a = reinterpret_cast<const float4*>(emb)[i];
    float4 b = reinterpret_cast<const float4*>(hn)[i];
    float4 r = make_float4(a.x + b.x, a.y + b.y, a.z + b.z, a.w + b.w);
    reinterpret_cast<float4*>(out)[i] = r;
}

// out += hn   (middle layer)
__global__ void accum_mid(const float* __restrict__ hn, float* __restrict__ out, int n4) {
    int i = blockIdx.x * blockDim.x + threadIdx.x;
    if (i >= n4) return;
    float4 a = reinterpret_cast<float4*>(out)[i];
    float4 b = reinterpret_cast<const float4*>(hn)[i];
    float4 r = make_float4(a.x + b.x, a.y + b.y, a.z + b.z, a.w + b.w);
    reinterpret_cast<float4*>(out)[i] = r;
}

// out = (out + hn) * 0.25   (last layer + mean over L+1=4 embeddings)
__global__ void accum_last(const float* __restrict__ hn, float* __restrict__ out, int n4) {
    int i = blockIdx.x * blockDim.x + threadIdx.x;
    if (i >= n4) return;
    float4 a = reinterpret_cast<float4*>(out)[i];
    float4 b = reinterpret_cast<const float4*>(hn)[i];
    float4 r = make_float4((a.x + b.x) * 0.25f, (a.y + b.y) * 0.25f,
                           (a.z + b.z) * 0.25f, (a.w + b.w) * 0.25f);
    reinterpret_cast<float4*>(out)[i] = r;
}

extern "C" void kernel_launch(void* const* d_in, const int* in_sizes, int n_in,
                              void* d_out, int out_size, void* d_ws, size_t ws_size,
                              hipStream_t stream) {
    const float* emb = (const float*)d_in[0];
    const int*   src = (const int*)d_in[1];
    const int*   dst = (const int*)d_in[2];
    const float* w   = (const float*)d_in[3];
    float* out = (float*)d_out;

    const int nNodes = in_sizes[0] / D_FEAT;   // 100000
    const int nE     = in_sizes[1];            // 1600000
    const size_t hbytes = (size_t)nNodes * D_FEAT * sizeof(float);  // 12.8 MB

    float* A = (float*)d_ws;
    float* B = (float*)((char*)d_ws + hbytes);

    const int n4 = nNodes * D_FEAT / 4;
    const dim3 blk(256);
    const int sgrid = (nE * 8 + 255) / 256;
    const int agrid = (n4 + 255) / 256;

    // layer 0: emb -> B
    hipMemsetAsync(B, 0, hbytes, stream);
    spmm_scatter<<<sgrid, blk, 0, stream>>>(src, dst, w, emb, B, nE);
    accum_first<<<agrid, blk, 0, stream>>>(emb, B, out, n4);

    // layer 1: B -> A
    hipMemsetAsync(A, 0, hbytes, stream);
    spmm_scatter<<<sgrid, blk, 0, stream>>>(src, dst, w, B, A, nE);
    accum_mid<<<agrid, blk, 0, stream>>>(A, out, n4);

    // layer 2: A -> B
    hipMemsetAsync(B, 0, hbytes, stream);
    spmm_scatter<<<sgrid, blk, 0, stream>>>(src, dst, w, A, B, nE);
    accum_last<<<agrid, blk, 0, stream>>>(B, out, n4);
}

// Round 2
// 456.434 us; speedup vs baseline: 4.3119x; 4.3119x over previous
//
#include <hip/hip_runtime.h>
#include <stdint.h>

#define DF 32
typedef unsigned long long u64;

// ======================= CSR prepass =======================

// degree histogram over dst (cnt must be zeroed)
__global__ void k_hist(const int* __restrict__ dst, int* __restrict__ cnt, int nE) {
    int i = blockIdx.x * blockDim.x + threadIdx.x;
    if (i < nE) atomicAdd(&cnt[dst[i]], 1);
}

// per-1024-chunk partial sums (256 threads, 4 elems each)
__global__ void k_partial(const int* __restrict__ cnt, int* __restrict__ part, int n) {
    __shared__ int sm[256];
    int t = threadIdx.x;
    int base = blockIdx.x * 1024 + t * 4;
    int s = 0;
#pragma unroll
    for (int j = 0; j < 4; j++) { int idx = base + j; if (idx < n) s += cnt[idx]; }
    sm[t] = s; __syncthreads();
    for (int off = 128; off > 0; off >>= 1) { if (t < off) sm[t] += sm[t + off]; __syncthreads(); }
    if (t == 0) part[blockIdx.x] = sm[0];
}

// exclusive scan of <=128 partials in one block
__global__ void k_scanpart(const int* __restrict__ part, int* __restrict__ partex, int np) {
    __shared__ int sm[128];
    int t = threadIdx.x;
    int v = (t < np) ? part[t] : 0;
    sm[t] = v; __syncthreads();
    for (int off = 1; off < 128; off <<= 1) {
        int u = (t >= off) ? sm[t - off] : 0; __syncthreads();
        sm[t] += u; __syncthreads();
    }
    if (t < np) partex[t] = sm[t] - v;
}

// per-chunk exclusive scan + chunk offset -> rowptr[0..n], cursor[0..n-1]
// NOTE: cnt and cursor may alias (each element read before written by its owner thread)
__global__ void k_scan(const int* __restrict__ cnt, const int* __restrict__ partex,
                       int* __restrict__ rowptr, int* __restrict__ cursor, int n) {
    __shared__ int sm[256];
    int t = threadIdx.x;
    int base = blockIdx.x * 1024 + t * 4;
    int c[4]; int s = 0;
#pragma unroll
    for (int j = 0; j < 4; j++) { int idx = base + j; c[j] = (idx < n) ? cnt[idx] : 0; s += c[j]; }
    sm[t] = s; __syncthreads();
    for (int off = 1; off < 256; off <<= 1) {
        int u = (t >= off) ? sm[t - off] : 0; __syncthreads();
        sm[t] += u; __syncthreads();
    }
    int run = partex[blockIdx.x] + sm[t] - s;
#pragma unroll
    for (int j = 0; j < 4; j++) {
        int idx = base + j;
        if (idx < n) { rowptr[idx] = run; cursor[idx] = run; run += c[j]; }
    }
    if (base <= n - 1 && n - 1 < base + 4) rowptr[n] = run;   // run == total here
}

// drop each edge into its CSR slot as packed (w<<32 | src)
__global__ void k_scatter(const int* __restrict__ src, const int* __restrict__ dst,
                          const float* __restrict__ w, int* __restrict__ cursor,
                          u64* __restrict__ packed, int nE) {
    int i = blockIdx.x * blockDim.x + threadIdx.x;
    if (i >= nE) return;
    int d = dst[i];
    int pos = atomicAdd(&cursor[d], 1);
    packed[pos] = ((u64)__float_as_uint(w[i]) << 32) | (unsigned)src[i];
}

// ======================= pull SpMM =======================
// half-wave per node: lane f (0..31) owns feature f. MODE: 0 first layer
// (out = emb + acc), 1 middle (out += acc), 2 last (out = (out+acc)*0.25, no hn)
template <int MODE>
__global__ void k_pull(const int* __restrict__ rowptr, const u64* __restrict__ packed,
                       const float* __restrict__ h, float* __restrict__ hn,
                       const float* __restrict__ emb, float* __restrict__ out, int n) {
    int gid = blockIdx.x * blockDim.x + threadIdx.x;
    int node = gid >> 5;
    int f = gid & 31;
    if (node >= n) return;
    int s0 = rowptr[node], s1 = rowptr[node + 1];
    float acc = 0.f;
    for (int i = s0; i < s1; i++) {
        u64 pk = packed[i];
        int s = (int)(unsigned)(pk & 0xffffffffu);
        float wt = __uint_as_float((unsigned)(pk >> 32));
        acc += wt * h[(size_t)s * DF + f];
    }
    size_t o = (size_t)node * DF + f;
    if (MODE == 0)      { hn[o] = acc; out[o] = emb[o] + acc; }
    else if (MODE == 1) { hn[o] = acc; out[o] += acc; }
    else                { out[o] = (out[o] + acc) * 0.25f; }
}

// ======================= fallback (R1 atomic path) =======================

__global__ void spmm_scatter(const int* __restrict__ src, const int* __restrict__ dst,
                             const float* __restrict__ w, const float* __restrict__ h,
                             float* __restrict__ hn, int nE) {
    int i = blockIdx.x * blockDim.x + threadIdx.x;
    int total = nE * 8;
    if (i >= total) return;
    int e = i >> 3, g = i & 7;
    int s = src[e], t = dst[e];
    float wt = w[e];
    float4 v = reinterpret_cast<const float4*>(h)[(size_t)s * 8 + g];
    float* p = hn + (size_t)t * DF + g * 4;
    atomicAdd(p + 0, v.x * wt); atomicAdd(p + 1, v.y * wt);
    atomicAdd(p + 2, v.z * wt); atomicAdd(p + 3, v.w * wt);
}
__global__ void accum_first(const float* __restrict__ emb, const float* __restrict__ hn,
                            float* __restrict__ out, int n4) {
    int i = blockIdx.x * blockDim.x + threadIdx.x;
    if (i >= n4) return;
    float4 a = reinterpret_cast<const float4*>(emb)[i];
    float4 b = reinterpret_cast<const float4*>(hn)[i];
    reinterpret_cast<float4*>(out)[i] = make_float4(a.x+b.x, a.y+b.y, a.z+b.z, a.w+b.w);
}
__global__ void accum_mid(const float* __restrict__ hn, float* __restrict__ out, int n4) {
    int i = blockIdx.x * blockDim.x + threadIdx.x;
    if (i >= n4) return;
    float4 a = reinterpret_cast<float4*>(out)[i];
    float4 b = reinterpret_cast<const float4*>(hn)[i];
    reinterpret_cast<float4*>(out)[i] = make_float4(a.x+b.x, a.y+b.y, a.z+b.z, a.w+b.w);
}
__global__ void accum_last(const float* __restrict__ hn, float* __restrict__ out, int n4) {
    int i = blockIdx.x * blockDim.x + threadIdx.x;
    if (i >= n4) return;
    float4 a = reinterpret_cast<float4*>(out)[i];
    float4 b = reinterpret_cast<const float4*>(hn)[i];
    reinterpret_cast<float4*>(out)[i] = make_float4((a.x+b.x)*0.25f, (a.y+b.y)*0.25f,
                                                    (a.z+b.z)*0.25f, (a.w+b.w)*0.25f);
}

// ======================= launch =======================

extern "C" void kernel_launch(void* const* d_in, const int* in_sizes, int n_in,
                              void* d_out, int out_size, void* d_ws, size_t ws_size,
                              hipStream_t stream) {
    const float* emb = (const float*)d_in[0];
    const int*   src = (const int*)d_in[1];
    const int*   dst = (const int*)d_in[2];
    const float* w   = (const float*)d_in[3];
    float* out = (float*)d_out;

    const int nN = in_sizes[0] / DF;        // 100000
    const int nE = in_sizes[1];             // 1600000
    const size_t hbytes = (size_t)nN * DF * sizeof(float);

    char* ws = (char*)d_ws;
    float* A = (float*)ws;
    float* B = (float*)(ws + hbytes);
    u64* packed = (u64*)(ws + 2 * hbytes);
    size_t roff = 3 * hbytes;
    int* rowptr = (int*)(ws + roff);
    size_t coff = roff + (((size_t)(nN + 1) * 4 + 63) / 64) * 64;
    int* cursor = (int*)(ws + coff);        // doubles as counts
    size_t poff = coff + (((size_t)nN * 4 + 63) / 64) * 64;
    int* part   = (int*)(ws + poff);
    int* partex = part + 128;

    const int NB = (nN + 1023) / 1024;      // scan chunks
    const size_t need = poff + 256 * sizeof(int) + 1024;

    const dim3 blk(256);

    if (ws_size >= need && NB <= 128) {
        // ---- build CSR ----
        hipMemsetAsync(cursor, 0, (size_t)nN * 4, stream);
        k_hist<<<(nE + 255) / 256, blk, 0, stream>>>(dst, cursor, nE);
        k_partial<<<NB, blk, 0, stream>>>(cursor, part, nN);
        k_scanpart<<<1, 128, 0, stream>>>(part, partex, NB);
        k_scan<<<NB, blk, 0, stream>>>(cursor, partex, rowptr, cursor, nN);
        k_scatter<<<(nE + 255) / 256, blk, 0, stream>>>(src, dst, w, cursor, packed, nE);

        // ---- 3 pull layers, accumulation fused ----
        const int pgrid = (nN * 32 + 255) / 256;
        k_pull<0><<<pgrid, blk, 0, stream>>>(rowptr, packed, emb, B, emb, out, nN);
        k_pull<1><<<pgrid, blk, 0, stream>>>(rowptr, packed, B,   A, emb, out, nN);
        k_pull<2><<<pgrid, blk, 0, stream>>>(rowptr, packed, A,   B, emb, out, nN);
    } else {
        // ---- fallback: atomic scatter path ----
        const int n4 = nN * DF / 4;
        const int sgrid = (nE * 8 + 255) / 256;
        const int agrid = (n4 + 255) / 256;
        hipMemsetAsync(B, 0, hbytes, stream);
        spmm_scatter<<<sgrid, blk, 0, stream>>>(src, dst, w, emb, B, nE);
        accum_first<<<agrid, blk, 0, stream>>>(emb, B, out, n4);
        hipMemsetAsync(A, 0, hbytes, stream);
        spmm_scatter<<<sgrid, blk, 0, stream>>>(src, dst, w, B, A, nE);
        accum_mid<<<agrid, blk, 0, stream>>>(A, out, n4);
        hipMemsetAsync(B, 0, hbytes, stream);
        spmm_scatter<<<sgrid, blk, 0, stream>>>(src, dst, w, A, B, nE);
        accum_last<<<agrid, blk, 0, stream>>>(B, out, n4);
    }
}